// Round 1
// baseline (2046.206 us; speedup 1.0000x reference)
//
#include <hip/hip_runtime.h>

// ---------------------------------------------------------------------------
// 2-layer tanh RNN, B=64, T=512, I=256, H=512.  Round 6: kill the degree-32
// all-gather.  Weight-fat persistent blocks:
//   - layer0: 4 groups x 2 col-half blocks (1024 thr, 16 waves); each wave
//     holds one 16-col tile of W_hh0 full-K in regs (64 VGPR); per-step sync
//     degree = 1 peer flag.  x@W_ih0+biases precomputed by a parallel GEMM
//     into d_out (consumed at step t strictly before layer1 overwrites it).
//   - layer1: 4 groups x 4 col-quarter blocks; wave pairs = (hh, ih) matmuls
//     full-K, pair-reduced via LDS; sync = 3 layer1 peers + 2 layer0 halves.
//   - per step each block cooperatively stages the [16][512] h-tile into
//     swizzled LDS (coalesced 16B/thread, one latency), then streams MFMA
//     A-fragments from LDS.  VGPR ~90, no spills.
//   - publish/poll machinery unchanged from validated R5 kernel (relaxed
//     agent atomics, vmcnt drain -> barrier -> one plain flag store,
//     first-touch rotating (T+1)-slab addressing).
// ---------------------------------------------------------------------------

#define kB 64
#define kT 512
#define kI 256
#define kH 512
#define kBH (kB * kH)   // 32768

typedef _Float16 half8 __attribute__((ext_vector_type(8)));
typedef float floatx4 __attribute__((ext_vector_type(4)));

// ws layout (bytes)
constexpr size_t W16_B   = 0;                                    // wih0 fp16, 256 KB
constexpr size_t OUT0M_B = 16u * 1024 * 1024;                    // [T+1][B][H] fp16
constexpr size_t H1M_B   = OUT0M_B + (size_t)(kT + 1) * kBH * 2; // [T+1][B][H] fp16
constexpr size_t CNT_B   = H1M_B + (size_t)(kT + 1) * kBH * 2;   // flags

__device__ inline half8 cvt8(const float* p) {
    const float4* p4 = (const float4*)p;
    float4 a = p4[0], b = p4[1];
    half8 h;
    h[0] = (_Float16)a.x; h[1] = (_Float16)a.y; h[2] = (_Float16)a.z; h[3] = (_Float16)a.w;
    h[4] = (_Float16)b.x; h[5] = (_Float16)b.y; h[6] = (_Float16)b.z; h[7] = (_Float16)b.w;
    return h;
}

__device__ inline void sc_store_half(_Float16* p, _Float16 v) {
    unsigned short u = __builtin_bit_cast(unsigned short, v);
    __hip_atomic_store((unsigned short*)p, u, __ATOMIC_RELAXED, __HIP_MEMORY_SCOPE_AGENT);
}

__device__ inline void wait_slot(const int* p, int target) {
    int guard = 0;
    while (__hip_atomic_load(p, __ATOMIC_RELAXED, __HIP_MEMORY_SCOPE_AGENT) < target)
        if (++guard > 100000000) break;   // fail-wrong, not hang
    asm volatile("" ::: "memory");        // keep gated loads below the gate
}

__device__ inline void wait_pair(const int* slots, int target) {
    const int* p = slots + (threadIdx.x & 1);
    int guard = 0;
    for (;;) {
        int v = __hip_atomic_load(p, __ATOMIC_RELAXED, __HIP_MEMORY_SCOPE_AGENT);
        if (__all(v >= target)) break;
        if (++guard > 100000000) break;
    }
    asm volatile("" ::: "memory");
}

__device__ inline void wait_quarters(const int* slots, int own, int target) {
    const int idx = threadIdx.x & 3;
    const int* p = slots + idx;
    int guard = 0;
    for (;;) {
        int v = (idx == own) ? target
              : __hip_atomic_load(p, __ATOMIC_RELAXED, __HIP_MEMORY_SCOPE_AGENT);
        if (__all(v >= target)) break;
        if (++guard > 100000000) break;
    }
    asm volatile("" ::: "memory");
}

// ---------------------------------------------------------------------------
__global__ void setup_kernel(const float* __restrict__ h0, const float* __restrict__ wih0,
                             _Float16* __restrict__ out0m, _Float16* __restrict__ h1m,
                             _Float16* __restrict__ w16, int* __restrict__ cnt) {
    int idx = blockIdx.x * blockDim.x + threadIdx.x;  // 0 .. 131071
    if (idx < kBH) out0m[idx] = (_Float16)h0[idx];                 // h(0) layer0
    else if (idx < 2 * kBH) h1m[idx - kBH] = (_Float16)h0[idx];    // h(0) layer1
    w16[idx] = (_Float16)wih0[idx];                                // kH*kI = 131072
    if (idx < 256) cnt[idx] = 0;
}

// xw[b][t][c] = sum_i x[b,t,i]*Wih0[c,i] + bih0[c] + bhh0[c]   (fp32, into d_out)
__global__ __launch_bounds__(256) void xw_kernel(
    const float* __restrict__ x, const _Float16* __restrict__ w16,
    const float* __restrict__ bih, const float* __restrict__ bhh, float* xw) {
    const int mb = blockIdx.x >> 3, nb = blockIdx.x & 7;
    const int wave = threadIdx.x >> 6, lane = threadIdx.x & 63;
    const int r = lane & 15, q = lane >> 4;
    const int m0 = mb * 64 + wave * 16;           // this wave's 16 rows of M=B*T
    half8 a[8];
#pragma unroll
    for (int ko = 0; ko < 8; ++ko)
        a[ko] = cvt8(x + (size_t)(m0 + r) * kI + ko * 32 + q * 8);
#pragma unroll
    for (int ct = 0; ct < 4; ++ct) {
        const int cc = nb * 64 + ct * 16 + r;
        const float bias = bih[cc] + bhh[cc];
        floatx4 acc = {bias, bias, bias, bias};
#pragma unroll
        for (int ko = 0; ko < 8; ++ko) {
            half8 b = *(const half8*)(w16 + (size_t)cc * kI + ko * 32 + q * 8);
            acc = __builtin_amdgcn_mfma_f32_16x16x32_f16(a[ko], b, acc, 0, 0, 0);
        }
#pragma unroll
        for (int j = 0; j < 4; ++j)
            xw[(size_t)(m0 + q * 4 + j) * kH + cc] = acc[j];
    }
}

// ---------------------------------------------------------------------------
__global__ __launch_bounds__(1024) void scan_kernel(
    const float* xw,                       // = d_out (fp32 [B][T][H]), layer0 reads
    _Float16* __restrict__ out0m, _Float16* __restrict__ h1m,
    int* __restrict__ slots0, int* __restrict__ slots1,
    float* out1,                           // = d_out, layer1 writes
    const float* __restrict__ whh0,
    const float* __restrict__ wih1, const float* __restrict__ whh1,
    const float* __restrict__ bih1, const float* __restrict__ bhh1) {
    __shared__ __align__(16) char smem[40960];  // [0,16K) tileA/H, [16K,32K) tileX, [32K,40K) red

    const int blk = blockIdx.x;
    const int tid = threadIdx.x;
    const int wave = tid >> 6, lane = tid & 63;
    const int r = lane & 15, q = lane >> 4;
    const int rb = (r << 10), swz = (r & 7) << 4;

    if (blk < 8) {
        // ---------------- layer 0: 2 col-half blocks x 4 groups ----------------
        const int g = blk >> 1, half = blk & 1;
        const int b0 = g * 16;
        const int cc = half * 256 + wave * 16 + r;   // weight row / output col
        half8 wfh[16];
#pragma unroll
        for (int ks = 0; ks < 16; ++ks)
            wfh[ks] = cvt8(whh0 + (size_t)cc * kH + ks * 32 + q * 8);
        int* myslot = slots0 + g * 2 + half;
        const int* peerslot = slots0 + g * 2 + (half ^ 1);
        // cooperative staging: one 16B unit / thread covers [16][512] fp16
        const int srow = tid >> 6, sunit = tid & 63;
        const size_t sg_off = (size_t)(b0 + srow) * kH + sunit * 8;
        char* sdst = smem + (((srow << 10) | (sunit << 4)) ^ ((srow & 7) << 4));

        for (int t = 0; t < kT; ++t) {
            float xwv[4];                 // prefetch xw (epilogue-only use)
#pragma unroll
            for (int j = 0; j < 4; ++j)
                xwv[j] = xw[((size_t)(b0 + q * 4 + j) * kT + t) * kH + cc];
            if (t > 0) wait_slot(peerslot, t);          // peer half of h(t)
            *(half8*)sdst = *(const half8*)(out0m + (size_t)t * kBH + sg_off);
            __syncthreads();                            // S: tile staged
            floatx4 acc = {0.f, 0.f, 0.f, 0.f};
#pragma unroll
            for (int ks = 0; ks < 16; ++ks) {
                half8 la = *(const half8*)(smem + ((rb | (ks << 6) | (q << 4)) ^ swz));
                acc = __builtin_amdgcn_mfma_f32_16x16x32_f16(la, wfh[ks], acc, 0, 0, 0);
            }
            _Float16* dst = out0m + (size_t)(t + 1) * kBH + (size_t)(b0 + q * 4) * kH + cc;
#pragma unroll
            for (int j = 0; j < 4; ++j)
                sc_store_half(dst + (size_t)j * kH, (_Float16)tanhf(acc[j] + xwv[j]));
            asm volatile("" ::: "memory");
            __builtin_amdgcn_s_waitcnt(0x0F70);         // vmcnt(0): drain this wave
            __syncthreads();                            // P: all waves drained
            if (tid == 0)
                __hip_atomic_store(myslot, t + 1, __ATOMIC_RELAXED, __HIP_MEMORY_SCOPE_AGENT);
        }
    } else {
        // ---------------- layer 1: 4 col-quarter blocks x 4 groups ----------------
        const int b2 = blk - 8;
        const int g = b2 >> 2, qb = b2 & 3;
        const int b0 = g * 16;
        const int ct = wave >> 1, part = wave & 1;      // pair: part0=hh, part1=ih
        const int cc = qb * 128 + ct * 16 + r;
        half8 wf[16];
        const float* wsrc = part ? wih1 : whh1;
#pragma unroll
        for (int ks = 0; ks < 16; ++ks)
            wf[ks] = cvt8(wsrc + (size_t)cc * kH + ks * 32 + q * 8);
        const float bias = (part == 0) ? (bih1[cc] + bhh1[cc]) : 0.f;
        int* myslot = slots1 + g * 4 + qb;
        const int* gq = slots1 + g * 4;                 // own-layer quarters
        const int* gh = slots0 + g * 2;                 // layer0 halves
        // staging: 512 threads per part, two 16B units each -> [16][512] fp16
        const int u = ct * 64 + lane;
        const int srow = u >> 5, sunit = u & 31;
        const size_t sg_off = (size_t)(b0 + srow) * kH + sunit * 16;
        const int tbase = part ? 16384 : 0;
        char* sd0 = smem + tbase + ((((srow << 10) | (sunit << 5))) ^ ((srow & 7) << 4));
        char* sd1 = smem + tbase + ((((srow << 10) | (sunit << 5)) | 16) ^ ((srow & 7) << 4));
        float* redp = (float*)(smem + 32768) + (ct * 256 + lane * 4);

        for (int t = 0; t < kT; ++t) {
            const _Float16* sl;
            if (part == 0) {                            // own h1(t) tile
                if (t > 0) wait_quarters(gq, qb, t);
                sl = h1m + (size_t)t * kBH;
            } else {                                    // layer0 output for step t
                wait_pair(gh, t + 1);
                sl = out0m + (size_t)(t + 1) * kBH;
            }
            half8 s0 = *(const half8*)(sl + sg_off);
            half8 s1 = *(const half8*)(sl + sg_off + 8);
            *(half8*)sd0 = s0;
            *(half8*)sd1 = s1;
            __syncthreads();                            // S: both tiles staged
            floatx4 acc = {0.f, 0.f, 0.f, 0.f};
            const char* tb = smem + tbase;
#pragma unroll
            for (int ks = 0; ks < 16; ++ks) {
                half8 la = *(const half8*)(tb + ((rb | (ks << 6) | (q << 4)) ^ swz));
                acc = __builtin_amdgcn_mfma_f32_16x16x32_f16(la, wf[ks], acc, 0, 0, 0);
            }
            if (part == 1) *(floatx4*)redp = acc;
            __syncthreads();                            // R: partials ready
            if (part == 0) {
                floatx4 o = *(const floatx4*)redp;
#pragma unroll
                for (int j = 0; j < 4; ++j) {
                    float v = tanhf(acc[j] + o[j] + bias);
                    out1[((size_t)(b0 + q * 4 + j) * kT + t) * kH + cc] = v;
                    sc_store_half(h1m + (size_t)(t + 1) * kBH + (size_t)(b0 + q * 4 + j) * kH + cc,
                                  (_Float16)v);
                }
            }
            asm volatile("" ::: "memory");
            __builtin_amdgcn_s_waitcnt(0x0F70);         // vmcnt(0)
            __syncthreads();                            // P
            if (tid == 0)
                __hip_atomic_store(myslot, t + 1, __ATOMIC_RELAXED, __HIP_MEMORY_SCOPE_AGENT);
        }
    }
}

__global__ void finalize_kernel(const _Float16* __restrict__ out0m,
                                const _Float16* __restrict__ h1m,
                                float* __restrict__ out) {
    int idx = blockIdx.x * blockDim.x + threadIdx.x;  // 0 .. 65535
    float* hn = out + (size_t)kB * kT * kH;
    if (idx < kBH) hn[idx] = (float)out0m[(size_t)kT * kBH + idx];
    else hn[idx] = (float)h1m[(size_t)kT * kBH + (idx - kBH)];
}

extern "C" void kernel_launch(void* const* d_in, const int* in_sizes, int n_in,
                              void* d_out, int out_size, void* d_ws, size_t ws_size,
                              hipStream_t stream) {
    const float* x    = (const float*)d_in[0];
    const float* h0in = (const float*)d_in[1];
    const float* wih0 = (const float*)d_in[2];
    const float* whh0 = (const float*)d_in[3];
    const float* bih0 = (const float*)d_in[4];
    const float* bhh0 = (const float*)d_in[5];
    const float* wih1 = (const float*)d_in[6];
    const float* whh1 = (const float*)d_in[7];
    const float* bih1 = (const float*)d_in[8];
    const float* bhh1 = (const float*)d_in[9];
    float* out = (float*)d_out;
    char* ws = (char*)d_ws;

    _Float16* w16   = (_Float16*)(ws + W16_B);
    _Float16* out0m = (_Float16*)(ws + OUT0M_B);
    _Float16* h1m   = (_Float16*)(ws + H1M_B);
    int* cnt        = (int*)(ws + CNT_B);
    int* slots0 = cnt;          // [4][2]
    int* slots1 = cnt + 32;     // [4][4]

    setup_kernel<<<512, 256, 0, stream>>>(h0in, wih0, out0m, h1m, w16, cnt);
    xw_kernel<<<4096, 256, 0, stream>>>(x, w16, bih0, bhh0, out);
    scan_kernel<<<24, 1024, 0, stream>>>(out, out0m, h1m, slots0, slots1, out,
                                         whh0, wih1, whh1, bih1, bhh1);
    finalize_kernel<<<256, 256, 0, stream>>>(out0m, h1m, out);
}